// Round 6
// baseline (58.974 us; speedup 1.0000x reference)
//
#include <hip/hip_runtime.h>

#define MARGIN 1.0f
#define LAMDA  0.003f
#define EPS_H  1e-9f

// constant term: LAMDA * 4 levels * (B*N=2048) * log(2*pi)
#define E2_CONST (0.003f * 4.0f * 2048.0f * 1.8378770664093453f)

__device__ __forceinline__ float finalize_level(const float* v) {
    const float Hxx = v[2] + EPS_H;
    const float Hxy = v[3];
    const float Hyy = v[4] + EPS_H;
    const float bX  = v[5];
    const float bY  = v[6];
    const float det = Hxx * Hyy - Hxy * Hxy;
    // e1_n = 0.5 * b^T H^{-1} b  (ub == xs so d = H^{-1} b exactly)
    const float e1  = 0.5f * (Hyy * bX * bX - 2.0f * Hxy * bX * bY + Hxx * bY * bY) / det;
    return (v[0] + v[1]) * (1.0f / 512.0f) + LAMDA * (e1 - 0.5f * logf(det));
}

// Full-point gather for one level: 8 independent loads/lane, lane == channel.
__device__ __forceinline__ void gather7(
    const float* __restrict__ fa, const float* __restrict__ fb,
    int2 kA, int2 kB, int2 nA, int2 nB,
    int shift, int S, int plane, float* v)
{
    const int kax = kA.x >> shift, kay = kA.y >> shift;
    const int kbx = kB.x >> shift, kby = kB.y >> shift;
    const int nax = nA.x >> shift, nay = nA.y >> shift;
    const int nbx = nB.x >> shift, nby = nB.y >> shift;

    const int   xm = (kbx > 0)     ? kbx - 1 : 0;
    const int   xp = (kbx < S - 1) ? kbx + 1 : S - 1;
    const float sx = (kbx > 0 && kbx < S - 1) ? 0.5f : 1.0f;
    const int   ym = (kby > 0)     ? kby - 1 : 0;
    const int   yp = (kby < S - 1) ? kby + 1 : S - 1;
    const float sy = (kby > 0 && kby < S - 1) ? 0.5f : 1.0f;

    const float va  = fa[plane + kay * S + kax];
    const float vna = fa[plane + nay * S + nax];
    const float vb  = fb[plane + kby * S + kbx];
    const float vnb = fb[plane + nby * S + nbx];
    const float gxm = fb[plane + kby * S + xm];
    const float gxp = fb[plane + kby * S + xp];
    const float gym = fb[plane + ym * S + kbx];
    const float gyp = fb[plane + yp * S + kbx];

    const float Jx = (gxp - gxm) * sx;
    const float Jy = (gyp - gym) * sy;

    const float dpos = va - vb;
    const float dneg = vna - vnb;
    const float mneg = fmaxf(MARGIN - dneg, 0.0f);
    const float r    = vb - va;

    v[0] = dpos * dpos;
    v[1] = mneg * mneg;
    v[2] = Jx * Jx;
    v[3] = Jx * Jy;
    v[4] = Jy * Jy;
    v[5] = Jx * r;
    v[6] = Jy * r;
}

// One wave (64 threads) per point; the wave does ALL FOUR levels -> 32
// independent gathers per lane in flight at once. Every wave is identical,
// so there is no tail where only expensive level-3 waves remain at low
// concurrency. No __syncthreads anywhere.
__global__ __launch_bounds__(64) void gn_task_kernel(
    const float* __restrict__ fa0, const float* __restrict__ fa1,
    const float* __restrict__ fa2, const float* __restrict__ fa3,
    const float* __restrict__ fb0, const float* __restrict__ fb1,
    const float* __restrict__ fb2, const float* __restrict__ fb3,
    const int* __restrict__ ka, const int* __restrict__ kb,
    const int* __restrict__ na, const int* __restrict__ nb,
    float* __restrict__ out)
{
    const int lane = threadIdx.x;             // lane == channel c (C = 64)
    const int n    = blockIdx.x;              // one point per wave
    const int b    = n >> 9;                  // N = 512

    // wave-uniform idx loads (compiler promotes to scalar loads)
    const int2 kA = ((const int2*)ka)[n];
    const int2 kB = ((const int2*)kb)[n];
    const int2 nA = ((const int2*)na)[n];
    const int2 nB = ((const int2*)nb)[n];

    const int base = (b * 64 + lane);
    const int plane0 = base * (32 * 32);
    const int plane1 = base * (64 * 64);
    const int plane2 = base * (128 * 128);
    const int plane3 = base * (256 * 256);

    float v[28];
    gather7(fa0, fb0, kA, kB, nA, nB, 3, 32,  plane0, v);
    gather7(fa1, fb1, kA, kB, nA, nB, 2, 64,  plane1, v + 7);
    gather7(fa2, fb2, kA, kB, nA, nB, 1, 128, plane2, v + 14);
    gather7(fa3, fb3, kA, kB, nA, nB, 0, 256, plane3, v + 21);

    // wave-wide (64-lane) butterfly reduction over all 28 partials
    #pragma unroll
    for (int mask = 32; mask >= 1; mask >>= 1)
        #pragma unroll
        for (int t = 0; t < 28; ++t)
            v[t] += __shfl_xor(v[t], mask, 64);

    if (lane == 0) {
        float s = finalize_level(v) + finalize_level(v + 7)
                + finalize_level(v + 14) + finalize_level(v + 21);
        if (n == 0) s += E2_CONST;
        atomicAdd(out, s);   // device-scope, 2048 atomics on one line
    }
}

extern "C" void kernel_launch(void* const* d_in, const int* in_sizes, int n_in,
                              void* d_out, int out_size, void* d_ws, size_t ws_size,
                              hipStream_t stream) {
    const float* fa0 = (const float*)d_in[0];
    const float* fa1 = (const float*)d_in[1];
    const float* fa2 = (const float*)d_in[2];
    const float* fa3 = (const float*)d_in[3];
    const float* fb0 = (const float*)d_in[4];
    const float* fb1 = (const float*)d_in[5];
    const float* fb2 = (const float*)d_in[6];
    const float* fb3 = (const float*)d_in[7];
    const int*   ka  = (const int*)d_in[8];
    const int*   kb  = (const int*)d_in[9];
    const int*   na  = (const int*)d_in[10];
    const int*   nb  = (const int*)d_in[11];

    float* out = (float*)d_out;
    hipMemsetAsync(out, 0, sizeof(float), stream);

    gn_task_kernel<<<2048, 64, 0, stream>>>(fa0, fa1, fa2, fa3,
                                            fb0, fb1, fb2, fb3,
                                            ka, kb, na, nb, out);
}

// Round 7
// 52.608 us; speedup vs baseline: 1.1210x; 1.1210x over previous
//
#include <hip/hip_runtime.h>

#define MARGIN 1.0f
#define LAMDA  0.003f
#define EPS_H  1e-9f

// constant term: LAMDA * 4 levels * (B*N=2048) * log(2*pi)
#define E2_CONST (0.003f * 4.0f * 2048.0f * 1.8378770664093453f)

__device__ __forceinline__ float finalize_level(const float* v) {
    const float Hxx = v[2] + EPS_H;
    const float Hxy = v[3];
    const float Hyy = v[4] + EPS_H;
    const float bX  = v[5];
    const float bY  = v[6];
    const float det = Hxx * Hyy - Hxy * Hxy;
    // e1_n = 0.5 * b^T H^{-1} b  (ub == xs so d = H^{-1} b exactly)
    const float e1  = 0.5f * (Hyy * bX * bX - 2.0f * Hxy * bX * bY + Hxx * bY * bY) / det;
    return (v[0] + v[1]) * (1.0f / 512.0f) + LAMDA * (e1 - 0.5f * logf(det));
}

// Full-point gather for one level: 8 independent loads/lane, lane == channel.
__device__ __forceinline__ void gather7(
    const float* __restrict__ fa, const float* __restrict__ fb,
    int2 kA, int2 kB, int2 nA, int2 nB,
    int shift, int S, int plane, float* v)
{
    const int kax = kA.x >> shift, kay = kA.y >> shift;
    const int kbx = kB.x >> shift, kby = kB.y >> shift;
    const int nax = nA.x >> shift, nay = nA.y >> shift;
    const int nbx = nB.x >> shift, nby = nB.y >> shift;

    const int   xm = (kbx > 0)     ? kbx - 1 : 0;
    const int   xp = (kbx < S - 1) ? kbx + 1 : S - 1;
    const float sx = (kbx > 0 && kbx < S - 1) ? 0.5f : 1.0f;
    const int   ym = (kby > 0)     ? kby - 1 : 0;
    const int   yp = (kby < S - 1) ? kby + 1 : S - 1;
    const float sy = (kby > 0 && kby < S - 1) ? 0.5f : 1.0f;

    const float va  = fa[plane + kay * S + kax];
    const float vna = fa[plane + nay * S + nax];
    const float vb  = fb[plane + kby * S + kbx];
    const float vnb = fb[plane + nby * S + nbx];
    const float gxm = fb[plane + kby * S + xm];
    const float gxp = fb[plane + kby * S + xp];
    const float gym = fb[plane + ym * S + kbx];
    const float gyp = fb[plane + yp * S + kbx];

    const float Jx = (gxp - gxm) * sx;
    const float Jy = (gyp - gym) * sy;

    const float dpos = va - vb;
    const float dneg = vna - vnb;
    const float mneg = fmaxf(MARGIN - dneg, 0.0f);
    const float r    = vb - va;

    v[0] = dpos * dpos;
    v[1] = mneg * mneg;
    v[2] = Jx * Jx;
    v[3] = Jx * Jy;
    v[4] = Jy * Jy;
    v[5] = Jx * r;
    v[6] = Jy * r;
}

// Block = 4 waves = 4 levels (level-balanced: no tail of expensive waves).
// Each wave handles its level for TWO ADJACENT points -> 16 independent
// gathers in flight per lane, while keeping the consecutive-point locality
// that distant pairing (R2) destroyed. 4096 waves total = 16 waves/CU.
__global__ __launch_bounds__(256) void gn_task_kernel(
    const float* __restrict__ fa0, const float* __restrict__ fa1,
    const float* __restrict__ fa2, const float* __restrict__ fa3,
    const float* __restrict__ fb0, const float* __restrict__ fb1,
    const float* __restrict__ fb2, const float* __restrict__ fb3,
    const int* __restrict__ ka, const int* __restrict__ kb,
    const int* __restrict__ na, const int* __restrict__ nb,
    float* __restrict__ out)
{
    __shared__ float wloss[4];

    const int wave  = threadIdx.x >> 6;
    const int lane  = threadIdx.x & 63;       // lane == channel c (C = 64)
    const int level = wave;
    const int shift = 3 - level;
    const int S     = 32 << level;

    const int n0 = blockIdx.x * 2;             // adjacent points
    const int n1 = n0 + 1;
    const int b  = n0 >> 9;                    // N = 512 (n0,n1 same batch)

    const float* fa; const float* fb;
    switch (level) {
        case 0:  fa = fa0; fb = fb0; break;
        case 1:  fa = fa1; fb = fb1; break;
        case 2:  fa = fa2; fb = fb2; break;
        default: fa = fa3; fb = fb3; break;
    }

    const int2 kA0 = ((const int2*)ka)[n0];
    const int2 kB0 = ((const int2*)kb)[n0];
    const int2 nA0 = ((const int2*)na)[n0];
    const int2 nB0 = ((const int2*)nb)[n0];
    const int2 kA1 = ((const int2*)ka)[n1];
    const int2 kB1 = ((const int2*)kb)[n1];
    const int2 nA1 = ((const int2*)na)[n1];
    const int2 nB1 = ((const int2*)nb)[n1];

    const int plane = (b * 64 + lane) * (S * S);

    float v[14];
    gather7(fa, fb, kA0, kB0, nA0, nB0, shift, S, plane, v);
    gather7(fa, fb, kA1, kB1, nA1, nB1, shift, S, plane, v + 7);

    // wave-wide (64-lane) butterfly reduction
    #pragma unroll
    for (int mask = 32; mask >= 1; mask >>= 1)
        #pragma unroll
        for (int t = 0; t < 14; ++t)
            v[t] += __shfl_xor(v[t], mask, 64);

    if (lane == 0)
        wloss[wave] = finalize_level(v) + finalize_level(v + 7);

    __syncthreads();
    if (threadIdx.x == 0) {
        float s = wloss[0] + wloss[1] + wloss[2] + wloss[3];
        if (blockIdx.x == 0) s += E2_CONST;
        atomicAdd(out, s);   // device-scope, 1024 atomics on one line
    }
}

extern "C" void kernel_launch(void* const* d_in, const int* in_sizes, int n_in,
                              void* d_out, int out_size, void* d_ws, size_t ws_size,
                              hipStream_t stream) {
    const float* fa0 = (const float*)d_in[0];
    const float* fa1 = (const float*)d_in[1];
    const float* fa2 = (const float*)d_in[2];
    const float* fa3 = (const float*)d_in[3];
    const float* fb0 = (const float*)d_in[4];
    const float* fb1 = (const float*)d_in[5];
    const float* fb2 = (const float*)d_in[6];
    const float* fb3 = (const float*)d_in[7];
    const int*   ka  = (const int*)d_in[8];
    const int*   kb  = (const int*)d_in[9];
    const int*   na  = (const int*)d_in[10];
    const int*   nb  = (const int*)d_in[11];

    float* out = (float*)d_out;
    hipMemsetAsync(out, 0, sizeof(float), stream);

    gn_task_kernel<<<1024, 256, 0, stream>>>(fa0, fa1, fa2, fa3,
                                             fb0, fb1, fb2, fb3,
                                             ka, kb, na, nb, out);
}

// Round 8
// 47.477 us; speedup vs baseline: 1.2422x; 1.1081x over previous
//
#include <hip/hip_runtime.h>

#define MARGIN 1.0f
#define LAMDA  0.003f
#define EPS_H  1e-9f

// constant term: LAMDA * 4 levels * (B*N=2048) * log(2*pi)
#define E2_CONST (0.003f * 4.0f * 2048.0f * 1.8378770664093453f)

__device__ __forceinline__ float finalize_level(const float* v) {
    const float Hxx = v[2] + EPS_H;
    const float Hxy = v[3];
    const float Hyy = v[4] + EPS_H;
    const float bX  = v[5];
    const float bY  = v[6];
    const float det = Hxx * Hyy - Hxy * Hxy;
    // e1_n = 0.5 * b^T H^{-1} b  (ub == xs so d = H^{-1} b exactly)
    const float e1  = 0.5f * (Hyy * bX * bX - 2.0f * Hxy * bX * bY + Hxx * bY * bY) / det;
    return (v[0] + v[1]) * (1.0f / 512.0f) + LAMDA * (e1 - 0.5f * logf(det));
}

// Full-point gather for one level: 8 independent loads/lane, lane == channel.
__device__ __forceinline__ void gather7(
    const float* __restrict__ fa, const float* __restrict__ fb,
    int2 kA, int2 kB, int2 nA, int2 nB,
    int shift, int S, int plane, float* v)
{
    const int kax = kA.x >> shift, kay = kA.y >> shift;
    const int kbx = kB.x >> shift, kby = kB.y >> shift;
    const int nax = nA.x >> shift, nay = nA.y >> shift;
    const int nbx = nB.x >> shift, nby = nB.y >> shift;

    const int   xm = (kbx > 0)     ? kbx - 1 : 0;
    const int   xp = (kbx < S - 1) ? kbx + 1 : S - 1;
    const float sx = (kbx > 0 && kbx < S - 1) ? 0.5f : 1.0f;
    const int   ym = (kby > 0)     ? kby - 1 : 0;
    const int   yp = (kby < S - 1) ? kby + 1 : S - 1;
    const float sy = (kby > 0 && kby < S - 1) ? 0.5f : 1.0f;

    const float va  = fa[plane + kay * S + kax];
    const float vna = fa[plane + nay * S + nax];
    const float vb  = fb[plane + kby * S + kbx];
    const float vnb = fb[plane + nby * S + nbx];
    const float gxm = fb[plane + kby * S + xm];
    const float gxp = fb[plane + kby * S + xp];
    const float gym = fb[plane + ym * S + kbx];
    const float gyp = fb[plane + yp * S + kbx];

    const float Jx = (gxp - gxm) * sx;
    const float Jy = (gyp - gym) * sy;

    const float dpos = va - vb;
    const float dneg = vna - vnb;
    const float mneg = fmaxf(MARGIN - dneg, 0.0f);
    const float r    = vb - va;

    v[0] = dpos * dpos;
    v[1] = mneg * mneg;
    v[2] = Jx * Jx;
    v[3] = Jx * Jy;
    v[4] = Jy * Jy;
    v[5] = Jx * r;
    v[6] = Jy * r;
}

// R7 structure + XCD-aware bijective swizzle: 1024 blocks = 8 XCDs x 128.
// Default dispatch round-robins blockIdx over XCDs, so the hot level-0/1
// planes get fetched independently into all 8 per-XCD L2s. The swizzle gives
// XCD x a CONTIGUOUS range of 128 blocks = 256 consecutive points = exactly
// one batch b = x/2 -> each XCD's L2 only sees its own batch's planes
// (level-0/1 slices ~6 MB become L2-resident instead of 8-way duplicated).
__global__ __launch_bounds__(256) void gn_task_kernel(
    const float* __restrict__ fa0, const float* __restrict__ fa1,
    const float* __restrict__ fa2, const float* __restrict__ fa3,
    const float* __restrict__ fb0, const float* __restrict__ fb1,
    const float* __restrict__ fb2, const float* __restrict__ fb3,
    const int* __restrict__ ka, const int* __restrict__ kb,
    const int* __restrict__ na, const int* __restrict__ nb,
    float* __restrict__ out)
{
    __shared__ float wloss[4];

    const int wave  = threadIdx.x >> 6;
    const int lane  = threadIdx.x & 63;       // lane == channel c (C = 64)
    const int level = wave;
    const int shift = 3 - level;
    const int S     = 32 << level;

    // bijective XCD swizzle (grid = 1024 = 8 * 128)
    const int bid = blockIdx.x;
    const int swz = (bid & 7) * 128 + (bid >> 3);

    const int n0 = swz * 2;                    // adjacent points
    const int n1 = n0 + 1;
    const int b  = n0 >> 9;                    // N = 512 (n0,n1 same batch)

    const float* fa; const float* fb;
    switch (level) {
        case 0:  fa = fa0; fb = fb0; break;
        case 1:  fa = fa1; fb = fb1; break;
        case 2:  fa = fa2; fb = fb2; break;
        default: fa = fa3; fb = fb3; break;
    }

    const int2 kA0 = ((const int2*)ka)[n0];
    const int2 kB0 = ((const int2*)kb)[n0];
    const int2 nA0 = ((const int2*)na)[n0];
    const int2 nB0 = ((const int2*)nb)[n0];
    const int2 kA1 = ((const int2*)ka)[n1];
    const int2 kB1 = ((const int2*)kb)[n1];
    const int2 nA1 = ((const int2*)na)[n1];
    const int2 nB1 = ((const int2*)nb)[n1];

    const int plane = (b * 64 + lane) * (S * S);

    float v[14];
    gather7(fa, fb, kA0, kB0, nA0, nB0, shift, S, plane, v);
    gather7(fa, fb, kA1, kB1, nA1, nB1, shift, S, plane, v + 7);

    // wave-wide (64-lane) butterfly reduction
    #pragma unroll
    for (int mask = 32; mask >= 1; mask >>= 1)
        #pragma unroll
        for (int t = 0; t < 14; ++t)
            v[t] += __shfl_xor(v[t], mask, 64);

    if (lane == 0)
        wloss[wave] = finalize_level(v) + finalize_level(v + 7);

    __syncthreads();
    if (threadIdx.x == 0) {
        float s = wloss[0] + wloss[1] + wloss[2] + wloss[3];
        if (bid == 0) s += E2_CONST;
        atomicAdd(out, s);   // device-scope, 1024 atomics on one line
    }
}

extern "C" void kernel_launch(void* const* d_in, const int* in_sizes, int n_in,
                              void* d_out, int out_size, void* d_ws, size_t ws_size,
                              hipStream_t stream) {
    const float* fa0 = (const float*)d_in[0];
    const float* fa1 = (const float*)d_in[1];
    const float* fa2 = (const float*)d_in[2];
    const float* fa3 = (const float*)d_in[3];
    const float* fb0 = (const float*)d_in[4];
    const float* fb1 = (const float*)d_in[5];
    const float* fb2 = (const float*)d_in[6];
    const float* fb3 = (const float*)d_in[7];
    const int*   ka  = (const int*)d_in[8];
    const int*   kb  = (const int*)d_in[9];
    const int*   na  = (const int*)d_in[10];
    const int*   nb  = (const int*)d_in[11];

    float* out = (float*)d_out;
    hipMemsetAsync(out, 0, sizeof(float), stream);

    gn_task_kernel<<<1024, 256, 0, stream>>>(fa0, fa1, fa2, fa3,
                                             fb0, fb1, fb2, fb3,
                                             ka, kb, na, nb, out);
}